// Round 3
// baseline (89.124 us; speedup 1.0000x reference)
//
#include <hip/hip_runtime.h>

#define HW 65536
#define Bn 4
#define Mn 100
#define Dn 128
#define GB 2048   // gather-kernel grid

// ---------------- K1: flags -> global balanced work list
__global__ __launch_bounds__(256) void flag_kernel(
    const float* __restrict__ boxes,
    unsigned int* __restrict__ gcount,
    unsigned int* __restrict__ cells)
{
    __shared__ float abox[Mn * 18];
    __shared__ int   am[Mn];
    __shared__ int   wcnt[4], wbase[4];
    __shared__ int   nactS, nflag;
    __shared__ unsigned int gbase;
    __shared__ int   clist[256];

    const int b  = blockIdx.x >> 8;
    const int y  = blockIdx.x & 255;
    const int tx = threadIdx.x;

    if (tx == 0) nflag = 0;

    const float DIMS0 = 51.2f + 51.2f;
    float gy = __fadd_rn(__fmul_rn((y + 0.5f) * (1.0f / 256.0f), DIMS0), -51.2f);

    // geometry in registers (exact arithmetic of the verified rounds)
    float px[4], py[4], ex[4], ey[4];
    bool act = false;
    if (tx < Mn) {
        const float* bx = boxes + (size_t)(b * Mn + tx) * 7;
        float cx = bx[0], cy = bx[1];
        float l = bx[3], w = bx[4], yaw = bx[6];
        const float cellw = DIMS0 / 256.0f;
        float rl = fminf(fmaxf(cellw / l, 1.0f), 6.0f);
        float rw = fminf(fmaxf(cellw / w, 1.0f), 6.0f);
        float el = __fmul_rn(l, rl);
        float ew = __fmul_rn(w, rw);
        float c = cosf(yaw), s = sinf(yaw);
        const float nx[4] = {-0.5f, -0.5f, 0.5f, 0.5f};
        const float ny[4] = {-0.5f, 0.5f, 0.5f, -0.5f};
        #pragma unroll
        for (int k = 0; k < 4; k++) {
            float ox = __fmul_rn(el, nx[k]);
            float oy = __fmul_rn(ew, ny[k]);
            float rx = __fadd_rn(__fmul_rn(ox, c), __fmul_rn(oy, s));
            float ry = __fadd_rn(__fmul_rn(-ox, s), __fmul_rn(oy, c));
            px[k] = __fadd_rn(rx, cx);
            py[k] = __fadd_rn(ry, cy);
        }
        #pragma unroll
        for (int k = 0; k < 4; k++) {
            ex[k] = __fsub_rn(px[(k + 1) & 3], px[k]);
            ey[k] = __fsub_rn(py[(k + 1) & 3], py[k]);
        }
        float r = 0.5f * sqrtf(el * el + ew * ew) + 0.01f;
        act = fabsf(gy - cy) <= r;       // conservative y-band
    }

    // order-preserving compaction of y-active boxes (m order preserved)
    unsigned long long mb = __ballot(act);
    int wid = tx >> 6;
    if ((tx & 63) == 0) wcnt[wid] = __popcll(mb);
    __syncthreads();
    if (tx == 0) {
        wbase[0] = 0;
        wbase[1] = wcnt[0];
        wbase[2] = wcnt[0] + wcnt[1];
        wbase[3] = wbase[2] + wcnt[2];
        nactS    = wbase[3] + wcnt[3];
    }
    __syncthreads();
    if (act) {
        int slot = wbase[wid] + __popcll(mb & ((1ull << (tx & 63)) - 1ull));
        float* o = abox + slot * 18;
        #pragma unroll
        for (int k = 0; k < 4; k++) {
            o[k * 2] = px[k];  o[k * 2 + 1] = py[k];
            o[8 + k * 2] = ex[k]; o[8 + k * 2 + 1] = ey[k];
        }
        am[slot] = tx;
    }
    __syncthreads();
    const int nact = nactS;

    // per-cell parity scan over the ~5 active boxes (broadcast LDS reads)
    float gx = __fadd_rn(__fmul_rn((tx + 0.5f) * (1.0f / 256.0f), DIMS0), -51.2f);
    int flag = -1;
    for (int j = 0; j < nact; j++) {
        const float* o = &abox[j * 18];
        bool ge = true, le = true;
        #pragma unroll
        for (int k = 0; k < 4; k++) {
            float dx = __fsub_rn(gx, o[k * 2]);
            float dy = __fsub_rn(gy, o[k * 2 + 1]);
            float cr = __fsub_rn(__fmul_rn(o[8 + k * 2], dy),
                                 __fmul_rn(o[8 + k * 2 + 1], dx));
            ge = ge && (cr >= 0.0f);
            le = le && (cr <= 0.0f);
        }
        if (ge || le) flag = (flag == -1) ? am[j] : -1;
    }

    if (flag >= 0) {
        int idx = atomicAdd(&nflag, 1);
        clist[idx] = (b << 23) | (flag << 16) | (y << 8) | tx;
    }
    __syncthreads();
    if (tx == 0) gbase = atomicAdd(gcount, (unsigned int)nflag);
    __syncthreads();
    for (int i = tx; i < nflag; i += 256) cells[gbase + i] = clist[i];
}

// ---------------- K2: balanced sparse variance gather + accumulate + finalize
__global__ __launch_bounds__(256) void gather_kernel(
    const float* __restrict__ atten,
    const unsigned int* __restrict__ cells,
    const unsigned int* __restrict__ gcount,
    float* __restrict__ gsum, float* __restrict__ gcnt,
    unsigned int* __restrict__ ticket, float* __restrict__ out)
{
    __shared__ float ssum[Bn * Mn], scnt[Bn * Mn];
    __shared__ int lastblk;
    const int tx = threadIdx.x;
    for (int i = tx; i < Bn * Mn; i += 256) { ssum[i] = 0.0f; scnt[i] = 0.0f; }
    __syncthreads();

    const unsigned int n = *gcount;
    const int g = tx >> 5, lane = tx & 31;
    for (unsigned int i = blockIdx.x * 8 + g; i < n; i += GB * 8) {
        unsigned int e = cells[i];
        int x = e & 255, y = (e >> 8) & 255, m = (e >> 16) & 127, b = (int)(e >> 23);
        const float4* p = reinterpret_cast<const float4*>(
            atten + (size_t)((b * 256 + y) * 256 + x) * Dn) + lane;
        float4 xv = *p;
        float s = xv.x + xv.y + xv.z + xv.w;
        float q = xv.x * xv.x + xv.y * xv.y + xv.z * xv.z + xv.w * xv.w;
        #pragma unroll
        for (int d = 16; d; d >>= 1) {
            s += __shfl_xor(s, d);
            q += __shfl_xor(q, d);
        }
        if (lane == 0) {
            float vv = (q - s * s * (1.0f / 128.0f)) * (1.0f / 127.0f);
            atomicAdd(&ssum[b * Mn + m], vv);
            atomicAdd(&scnt[b * Mn + m], 1.0f);
        }
    }
    __syncthreads();
    for (int i = tx; i < Bn * Mn; i += 256) {
        float c = scnt[i];
        if (c > 0.0f) {
            atomicAdd(&gsum[i], ssum[i]);
            atomicAdd(&gcnt[i], c);
        }
    }
    __syncthreads();

    if (tx == 0) {
        __threadfence();
        unsigned int t = __hip_atomic_fetch_add(ticket, 1u, __ATOMIC_ACQ_REL,
                                                __HIP_MEMORY_SCOPE_AGENT);
        lastblk = (t == (unsigned int)(GB - 1)) ? 1 : 0;
    }
    __syncthreads();
    if (!lastblk) return;
    __threadfence();

    float loss = 0.0f, num = 0.0f;
    for (int i = tx; i < Bn * Mn; i += 256) {
        float c = __hip_atomic_load(&gcnt[i], __ATOMIC_RELAXED, __HIP_MEMORY_SCOPE_AGENT);
        if (c > 0.0f) {
            float sL = __hip_atomic_load(&gsum[i], __ATOMIC_RELAXED, __HIP_MEMORY_SCOPE_AGENT);
            loss -= sL / fmaxf(c, 1.0f);
            num  += 1.0f;
        }
    }
    #pragma unroll
    for (int d = 32; d; d >>= 1) {
        loss += __shfl_xor(loss, d);
        num  += __shfl_xor(num, d);
    }
    if ((tx & 63) == 0) { ssum[tx >> 6] = loss; scnt[tx >> 6] = num; }
    __syncthreads();
    if (tx == 0) {
        float L = ssum[0] + ssum[1] + ssum[2] + ssum[3];
        float N = scnt[0] + scnt[1] + scnt[2] + scnt[3];
        out[0] = L / fmaxf(N, 1.0f);
    }
}

extern "C" void kernel_launch(void* const* d_in, const int* in_sizes, int n_in,
                              void* d_out, int out_size, void* d_ws, size_t ws_size,
                              hipStream_t stream) {
    const float* atten = (const float*)d_in[0];
    const float* boxes = (const float*)d_in[1];
    float* out = (float*)d_out;

    // ws layout: gsum[400] | gcnt[400] | ticket | gcount | pad ... cells @ +4096
    float* gsum = (float*)d_ws;
    float* gcnt = gsum + Bn * Mn;
    unsigned int* ticket = (unsigned int*)(gcnt + Bn * Mn);
    unsigned int* gcount = ticket + 1;
    unsigned int* cells  = (unsigned int*)((char*)d_ws + 4096);  // up to 262144 entries = 1 MB

    hipMemsetAsync(d_ws, 0, 4096, stream);
    flag_kernel<<<Bn * 256, 256, 0, stream>>>(boxes, gcount, cells);
    gather_kernel<<<GB, 256, 0, stream>>>(atten, cells, gcount, gsum, gcnt, ticket, out);
}

// Round 4
// 34.263 us; speedup vs baseline: 2.6012x; 2.6012x over previous
//
#include <hip/hip_runtime.h>

#define Bn 4
#define Mn 100
#define Dn 128
#define GB 2048   // gather-kernel grid

// ---------------- K1: flags -> global balanced work list (no fences)
__global__ __launch_bounds__(256) void flag_kernel(
    const float* __restrict__ boxes,
    unsigned int* __restrict__ gcount,
    unsigned int* __restrict__ cells)
{
    __shared__ float abox[Mn * 18];
    __shared__ int   am[Mn];
    __shared__ int   wcnt[4], wbase[4];
    __shared__ int   nactS, nflag;
    __shared__ unsigned int gbase;
    __shared__ int   clist[256];

    const int b  = blockIdx.x >> 8;
    const int y  = blockIdx.x & 255;
    const int tx = threadIdx.x;

    if (tx == 0) nflag = 0;

    const float DIMS0 = 51.2f + 51.2f;
    float gy = __fadd_rn(__fmul_rn((y + 0.5f) * (1.0f / 256.0f), DIMS0), -51.2f);

    // geometry in registers (exact arithmetic of the verified rounds)
    float px[4], py[4], ex[4], ey[4];
    bool act = false;
    if (tx < Mn) {
        const float* bx = boxes + (size_t)(b * Mn + tx) * 7;
        float cx = bx[0], cy = bx[1];
        float l = bx[3], w = bx[4], yaw = bx[6];
        const float cellw = DIMS0 / 256.0f;
        float rl = fminf(fmaxf(cellw / l, 1.0f), 6.0f);
        float rw = fminf(fmaxf(cellw / w, 1.0f), 6.0f);
        float el = __fmul_rn(l, rl);
        float ew = __fmul_rn(w, rw);
        float c = cosf(yaw), s = sinf(yaw);
        const float nx[4] = {-0.5f, -0.5f, 0.5f, 0.5f};
        const float ny[4] = {-0.5f, 0.5f, 0.5f, -0.5f};
        #pragma unroll
        for (int k = 0; k < 4; k++) {
            float ox = __fmul_rn(el, nx[k]);
            float oy = __fmul_rn(ew, ny[k]);
            float rx = __fadd_rn(__fmul_rn(ox, c), __fmul_rn(oy, s));
            float ry = __fadd_rn(__fmul_rn(-ox, s), __fmul_rn(oy, c));
            px[k] = __fadd_rn(rx, cx);
            py[k] = __fadd_rn(ry, cy);
        }
        #pragma unroll
        for (int k = 0; k < 4; k++) {
            ex[k] = __fsub_rn(px[(k + 1) & 3], px[k]);
            ey[k] = __fsub_rn(py[(k + 1) & 3], py[k]);
        }
        float r = 0.5f * sqrtf(el * el + ew * ew) + 0.01f;
        act = fabsf(gy - cy) <= r;       // conservative y-band
    }

    // order-preserving compaction of y-active boxes (m order preserved)
    unsigned long long mb = __ballot(act);
    int wid = tx >> 6;
    if ((tx & 63) == 0) wcnt[wid] = __popcll(mb);
    __syncthreads();
    if (tx == 0) {
        wbase[0] = 0;
        wbase[1] = wcnt[0];
        wbase[2] = wcnt[0] + wcnt[1];
        wbase[3] = wbase[2] + wcnt[2];
        nactS    = wbase[3] + wcnt[3];
    }
    __syncthreads();
    if (act) {
        int slot = wbase[wid] + __popcll(mb & ((1ull << (tx & 63)) - 1ull));
        float* o = abox + slot * 18;
        #pragma unroll
        for (int k = 0; k < 4; k++) {
            o[k * 2] = px[k];  o[k * 2 + 1] = py[k];
            o[8 + k * 2] = ex[k]; o[8 + k * 2 + 1] = ey[k];
        }
        am[slot] = tx;
    }
    __syncthreads();
    const int nact = nactS;

    // per-cell parity scan over the ~5 y-active boxes (broadcast LDS reads)
    float gx = __fadd_rn(__fmul_rn((tx + 0.5f) * (1.0f / 256.0f), DIMS0), -51.2f);
    int flag = -1;
    for (int j = 0; j < nact; j++) {
        const float* o = &abox[j * 18];
        bool ge = true, le = true;
        #pragma unroll
        for (int k = 0; k < 4; k++) {
            float dx = __fsub_rn(gx, o[k * 2]);
            float dy = __fsub_rn(gy, o[k * 2 + 1]);
            float cr = __fsub_rn(__fmul_rn(o[8 + k * 2], dy),
                                 __fmul_rn(o[8 + k * 2 + 1], dx));
            ge = ge && (cr >= 0.0f);
            le = le && (cr <= 0.0f);
        }
        if (ge || le) flag = (flag == -1) ? am[j] : -1;
    }

    if (flag >= 0) {
        int idx = atomicAdd(&nflag, 1);
        clist[idx] = (b << 23) | (flag << 16) | (y << 8) | tx;
    }
    __syncthreads();
    if (tx == 0) gbase = atomicAdd(gcount, (unsigned int)nflag);
    __syncthreads();
    for (int i = tx; i < nflag; i += 256) cells[gbase + i] = clist[i];
}

// ---------------- K2: balanced sparse variance gather (no ticket, no fence)
__global__ __launch_bounds__(256) void gather_kernel(
    const float* __restrict__ atten,
    const unsigned int* __restrict__ cells,
    const unsigned int* __restrict__ gcount,
    float* __restrict__ gsum, float* __restrict__ gcnt)
{
    __shared__ float ssum[Bn * Mn], scnt[Bn * Mn];
    const int tx = threadIdx.x;
    for (int i = tx; i < Bn * Mn; i += 256) { ssum[i] = 0.0f; scnt[i] = 0.0f; }
    __syncthreads();

    const unsigned int n = *gcount;
    const int g = tx >> 5, lane = tx & 31;
    for (unsigned int i = blockIdx.x * 8 + g; i < n; i += GB * 8) {
        unsigned int e = cells[i];
        int x = e & 255, y = (e >> 8) & 255, m = (e >> 16) & 127, b = (int)(e >> 23);
        const float4* p = reinterpret_cast<const float4*>(
            atten + (size_t)((b * 256 + y) * 256 + x) * Dn) + lane;
        float4 xv = *p;
        float s = xv.x + xv.y + xv.z + xv.w;
        float q = xv.x * xv.x + xv.y * xv.y + xv.z * xv.z + xv.w * xv.w;
        #pragma unroll
        for (int d = 16; d; d >>= 1) {
            s += __shfl_xor(s, d);
            q += __shfl_xor(q, d);
        }
        if (lane == 0) {
            float vv = (q - s * s * (1.0f / 128.0f)) * (1.0f / 127.0f);
            atomicAdd(&ssum[b * Mn + m], vv);
            atomicAdd(&scnt[b * Mn + m], 1.0f);
        }
    }
    __syncthreads();
    for (int i = tx; i < Bn * Mn; i += 256) {
        float c = scnt[i];
        if (c > 0.0f) {
            atomicAdd(&gsum[i], ssum[i]);
            atomicAdd(&gcnt[i], c);
        }
    }
}

// ---------------- K3: finalize scalar loss (1 block; R1-verified pattern)
__global__ __launch_bounds__(512) void final_kernel(const float* __restrict__ gsum,
                                                    const float* __restrict__ gcnt,
                                                    float* __restrict__ out) {
    __shared__ float sl[8], sn[8];
    int t = threadIdx.x;
    float loss = 0.0f, num = 0.0f;
    if (t < Bn * Mn) {
        float c = gcnt[t];
        if (c > 0.0f) {
            loss = -(gsum[t] / fmaxf(c, 1.0f));
            num = 1.0f;
        }
    }
    #pragma unroll
    for (int m = 32; m; m >>= 1) {
        loss += __shfl_xor(loss, m);
        num  += __shfl_xor(num, m);
    }
    if ((t & 63) == 0) { sl[t >> 6] = loss; sn[t >> 6] = num; }
    __syncthreads();
    if (t == 0) {
        float L = 0.0f, N = 0.0f;
        #pragma unroll
        for (int i = 0; i < 8; i++) { L += sl[i]; N += sn[i]; }
        out[0] = L / fmaxf(N, 1.0f);
    }
}

extern "C" void kernel_launch(void* const* d_in, const int* in_sizes, int n_in,
                              void* d_out, int out_size, void* d_ws, size_t ws_size,
                              hipStream_t stream) {
    const float* atten = (const float*)d_in[0];
    const float* boxes = (const float*)d_in[1];
    float* out = (float*)d_out;

    // ws layout: gsum[400] | gcnt[400] | gcount | pad ... cells @ +4096
    float* gsum = (float*)d_ws;
    float* gcnt = gsum + Bn * Mn;
    unsigned int* gcount = (unsigned int*)(gcnt + Bn * Mn);
    unsigned int* cells  = (unsigned int*)((char*)d_ws + 4096);  // up to 262144 entries = 1 MB

    hipMemsetAsync(d_ws, 0, 4096, stream);
    flag_kernel<<<Bn * 256, 256, 0, stream>>>(boxes, gcount, cells);
    gather_kernel<<<GB, 256, 0, stream>>>(atten, cells, gcount, gsum, gcnt);
    final_kernel<<<1, 512, 0, stream>>>(gsum, gcnt, out);
}

// Round 5
// 20.488 us; speedup vs baseline: 4.3501x; 1.6723x over previous
//
#include <hip/hip_runtime.h>

#define Bn 4
#define Mn 100
#define Dn 128

// ---------------- K1: flags -> deterministic per-row cell lists (no global atomics)
__global__ __launch_bounds__(256) void flag_kernel(
    const float* __restrict__ boxes,
    unsigned int* __restrict__ rowcnt,
    unsigned int* __restrict__ cells,
    float* __restrict__ gz)            // gsum|gcnt region: 2*Bn*Mn floats
{
    __shared__ float abox[Mn * 18];
    __shared__ int   am[Mn];
    __shared__ int   wcnt[4], wbase[4];
    __shared__ int   nactS, nflag;
    __shared__ int   clist[256];

    const int b  = blockIdx.x >> 8;
    const int y  = blockIdx.x & 255;
    const int tx = threadIdx.x;

    // zero the accumulator region (visible to gather via kernel boundary)
    if (blockIdx.x < 2 * Bn * Mn && tx == 0) gz[blockIdx.x] = 0.0f;
    if (tx == 0) nflag = 0;

    const float DIMS0 = 51.2f + 51.2f;
    float gy = __fadd_rn(__fmul_rn((y + 0.5f) * (1.0f / 256.0f), DIMS0), -51.2f);

    // geometry in registers (exact arithmetic of the verified rounds)
    float px[4], py[4], ex[4], ey[4];
    bool act = false;
    if (tx < Mn) {
        const float* bx = boxes + (size_t)(b * Mn + tx) * 7;
        float cx = bx[0], cy = bx[1];
        float l = bx[3], w = bx[4], yaw = bx[6];
        const float cellw = DIMS0 / 256.0f;
        float rl = fminf(fmaxf(cellw / l, 1.0f), 6.0f);
        float rw = fminf(fmaxf(cellw / w, 1.0f), 6.0f);
        float el = __fmul_rn(l, rl);
        float ew = __fmul_rn(w, rw);
        float c = cosf(yaw), s = sinf(yaw);
        const float nx[4] = {-0.5f, -0.5f, 0.5f, 0.5f};
        const float ny[4] = {-0.5f, 0.5f, 0.5f, -0.5f};
        #pragma unroll
        for (int k = 0; k < 4; k++) {
            float ox = __fmul_rn(el, nx[k]);
            float oy = __fmul_rn(ew, ny[k]);
            float rx = __fadd_rn(__fmul_rn(ox, c), __fmul_rn(oy, s));
            float ry = __fadd_rn(__fmul_rn(-ox, s), __fmul_rn(oy, c));
            px[k] = __fadd_rn(rx, cx);
            py[k] = __fadd_rn(ry, cy);
        }
        #pragma unroll
        for (int k = 0; k < 4; k++) {
            ex[k] = __fsub_rn(px[(k + 1) & 3], px[k]);
            ey[k] = __fsub_rn(py[(k + 1) & 3], py[k]);
        }
        float r = 0.5f * sqrtf(el * el + ew * ew) + 0.01f;
        act = fabsf(gy - cy) <= r;       // conservative y-band
    }

    // order-preserving compaction of y-active boxes (m order preserved)
    unsigned long long mb = __ballot(act);
    int wid = tx >> 6;
    if ((tx & 63) == 0) wcnt[wid] = __popcll(mb);
    __syncthreads();
    if (tx == 0) {
        wbase[0] = 0;
        wbase[1] = wcnt[0];
        wbase[2] = wcnt[0] + wcnt[1];
        wbase[3] = wbase[2] + wcnt[2];
        nactS    = wbase[3] + wcnt[3];
    }
    __syncthreads();
    const int nact = nactS;
    if (nact == 0) {                      // no box touches this row
        if (tx == 0) rowcnt[blockIdx.x] = 0;
        return;
    }
    if (act) {
        int slot = wbase[wid] + __popcll(mb & ((1ull << (tx & 63)) - 1ull));
        float* o = abox + slot * 18;
        #pragma unroll
        for (int k = 0; k < 4; k++) {
            o[k * 2] = px[k];  o[k * 2 + 1] = py[k];
            o[8 + k * 2] = ex[k]; o[8 + k * 2 + 1] = ey[k];
        }
        am[slot] = tx;
    }
    __syncthreads();

    // per-cell parity scan over the ~5 y-active boxes (broadcast LDS reads)
    float gx = __fadd_rn(__fmul_rn((tx + 0.5f) * (1.0f / 256.0f), DIMS0), -51.2f);
    int flag = -1;
    for (int j = 0; j < nact; j++) {
        const float* o = &abox[j * 18];
        bool ge = true, le = true;
        #pragma unroll
        for (int k = 0; k < 4; k++) {
            float dx = __fsub_rn(gx, o[k * 2]);
            float dy = __fsub_rn(gy, o[k * 2 + 1]);
            float cr = __fsub_rn(__fmul_rn(o[8 + k * 2], dy),
                                 __fmul_rn(o[8 + k * 2 + 1], dx));
            ge = ge && (cr >= 0.0f);
            le = le && (cr <= 0.0f);
        }
        if (ge || le) flag = (flag == -1) ? am[j] : -1;
    }

    if (flag >= 0) {
        int idx = atomicAdd(&nflag, 1);
        clist[idx] = (flag << 8) | tx;    // m (7b) | x (8b)
    }
    __syncthreads();
    if (tx == 0) rowcnt[blockIdx.x] = nflag;
    for (int i = tx; i < nflag; i += 256)
        cells[(blockIdx.x << 8) + i] = clist[i];
}

// ---------------- K2: sparse variance gather, 2 blocks per row (16 lane-groups)
__global__ __launch_bounds__(256) void gather_kernel(
    const float* __restrict__ atten,
    const unsigned int* __restrict__ rowcnt,
    const unsigned int* __restrict__ cells,
    float* __restrict__ gsum, float* __restrict__ gcnt)
{
    __shared__ float ssum[Mn], scnt[Mn];
    const int tx  = threadIdx.x;
    const int row = blockIdx.x >> 1;        // 0..1023 = b*256+y
    const int b   = row >> 8;
    const unsigned int n = rowcnt[row];

    if (tx < Mn) { ssum[tx] = 0.0f; scnt[tx] = 0.0f; }
    if (n == 0) return;
    __syncthreads();

    const int g = ((blockIdx.x & 1) << 3) + (tx >> 5);   // 0..15
    const int lane = tx & 31;
    const unsigned int base = (unsigned int)row << 8;
    for (unsigned int j = g; j < n; j += 16) {
        unsigned int e = cells[base + j];
        int x = e & 255, m = e >> 8;
        const float4* p = reinterpret_cast<const float4*>(
            atten + ((size_t)base + x) * Dn) + lane;     // row*256+x is flat row idx
        float4 xv = *p;
        float s = xv.x + xv.y + xv.z + xv.w;
        float q = xv.x * xv.x + xv.y * xv.y + xv.z * xv.z + xv.w * xv.w;
        #pragma unroll
        for (int d = 16; d; d >>= 1) {
            s += __shfl_xor(s, d);
            q += __shfl_xor(q, d);
        }
        if (lane == 0) {
            float vv = (q - s * s * (1.0f / 128.0f)) * (1.0f / 127.0f);
            atomicAdd(&ssum[m], vv);
            atomicAdd(&scnt[m], 1.0f);
        }
    }
    __syncthreads();
    if (tx < Mn && scnt[tx] > 0.0f) {
        atomicAdd(&gsum[b * Mn + tx], ssum[tx]);
        atomicAdd(&gcnt[b * Mn + tx], scnt[tx]);
    }
}

// ---------------- K3: finalize scalar loss (1 block; verified pattern)
__global__ __launch_bounds__(512) void final_kernel(const float* __restrict__ gsum,
                                                    const float* __restrict__ gcnt,
                                                    float* __restrict__ out) {
    __shared__ float sl[8], sn[8];
    int t = threadIdx.x;
    float loss = 0.0f, num = 0.0f;
    if (t < Bn * Mn) {
        float c = gcnt[t];
        if (c > 0.0f) {
            loss = -(gsum[t] / fmaxf(c, 1.0f));
            num = 1.0f;
        }
    }
    #pragma unroll
    for (int m = 32; m; m >>= 1) {
        loss += __shfl_xor(loss, m);
        num  += __shfl_xor(num, m);
    }
    if ((t & 63) == 0) { sl[t >> 6] = loss; sn[t >> 6] = num; }
    __syncthreads();
    if (t == 0) {
        float L = 0.0f, N = 0.0f;
        #pragma unroll
        for (int i = 0; i < 8; i++) { L += sl[i]; N += sn[i]; }
        out[0] = L / fmaxf(N, 1.0f);
    }
}

extern "C" void kernel_launch(void* const* d_in, const int* in_sizes, int n_in,
                              void* d_out, int out_size, void* d_ws, size_t ws_size,
                              hipStream_t stream) {
    const float* atten = (const float*)d_in[0];
    const float* boxes = (const float*)d_in[1];
    float* out = (float*)d_out;

    // ws layout: gsum[400] | gcnt[400] | rowcnt[1024] @+3200 | cells @+8192 (1 MB)
    float* gsum = (float*)d_ws;
    float* gcnt = gsum + Bn * Mn;
    unsigned int* rowcnt = (unsigned int*)((char*)d_ws + 3200);
    unsigned int* cells  = (unsigned int*)((char*)d_ws + 8192);

    flag_kernel<<<Bn * 256, 256, 0, stream>>>(boxes, rowcnt, cells, gsum);
    gather_kernel<<<2 * Bn * 256, 256, 0, stream>>>(atten, rowcnt, cells, gsum, gcnt);
    final_kernel<<<1, 512, 0, stream>>>(gsum, gcnt, out);
}